// Round 13
// baseline (189.146 us; speedup 1.0000x reference)
//
#include <hip/hip_runtime.h>

typedef __attribute__((ext_vector_type(8))) short bhalf8_t;   // 8 bf16 bit patterns
typedef __attribute__((ext_vector_type(4))) float f32x4_t;

// Problem constants (B=1, H=W=128, N=4, C=8, OUT=64, M=9, V=81)
// Positions P = 65,536. GEMM: M=P, K=648 pad 672 = 21x32, N=64. k' = v*8+c.
#define KCHUNKS 21
#define NPOS 65536
#define W_BYTES 172032                    // ushort[21][2][4][64][8]
#define T_BYTES 42467328                  // 81*128*128*8*4
#define VIEW_FLOATS 131072                // 128*128*8
#define CHUNK_BYTES (4 * VIEW_FLOATS * 4)

// ---------------------------------------------------------------------------
// Weight prep: 64 blocks (one per o), coalesced row stage.
// WtP[kc][hi|lo][g][o][e] = split-bf16 of conv_w[o][c*81+v], v=kc*4+g, c=e.
// ---------------------------------------------------------------------------
__global__ __launch_bounds__(256) void prep_w_kernel(
    const float* __restrict__ cw, unsigned short* __restrict__ WtP)
{
    __shared__ float row[648];
    const int o = blockIdx.x, t = threadIdx.x;
    for (int i = t; i < 648; i += 256) row[i] = cw[o * 648 + i];
    __syncthreads();
    for (int k = t; k < 672; k += 256) {
        const int v = k >> 3, c = k & 7;
        const float val = (v < 81) ? row[c * 81 + v] : 0.0f;
        const unsigned int hb = __float_as_uint(val) & 0xffff0000u;
        const float r = val - __uint_as_float(hb);
        const unsigned int lb = __float_as_uint(r) & 0xffff0000u;
        const int kc = k >> 5, g = (k >> 3) & 3, e = k & 7;
        const int ix = kc * 4096 + g * 512 + o * 8 + e;
        WtP[ix]        = (unsigned short)(hb >> 16);
        WtP[ix + 2048] = (unsigned short)(lb >> 16);
    }
}

// ---------------------------------------------------------------------------
// Full transpose: img [y][x][c][v] -> T [v][y][x][c] fp32 (pow-2 math only).
// ---------------------------------------------------------------------------
__global__ __launch_bounds__(256) void prep_T_all(
    const float* __restrict__ img, float* __restrict__ T)
{
    __shared__ float tile[16 * 8 * 85];   // [x][c][vi], odd pitch
    const int b = blockIdx.x, t = threadIdx.x;
    const int y = b >> 3, xs = (b & 7) << 4;
    const float* src = img + (size_t)(y * 128 + xs) * 648;
#pragma unroll
    for (int k = 0; k < 64; ++k) {
        const int i = t + k * 256;
        const int vi = i & 127;
        const int c = (i >> 7) & 7;
        const int x = i >> 10;
        if (vi < 81)
            tile[(x * 8 + c) * 85 + vi] = src[x * 648 + c * 81 + vi];
    }
    __syncthreads();
#pragma unroll
    for (int k = 0; k < 64; ++k) {
        const int i = t + k * 256;
        const int vi = i >> 7;
        const int x = (i >> 3) & 15;
        const int c = i & 7;
        if (vi < 81)
            T[((size_t)(vi * 128 + y) * 128 + xs + x) * 8 + c] =
                tile[(x * 8 + c) * 85 + vi];
    }
}

// Partial transpose for small-ws multi-pass path.
__global__ __launch_bounds__(256) void prep_T_pass(
    const float* __restrict__ img, float* __restrict__ T, int v0, int nv)
{
    __shared__ float tile[16 * 8 * 85];
    const int b = blockIdx.x, t = threadIdx.x;
    const int y = b >> 3, xs = (b & 7) << 4;
    const int total = 16 * 8 * nv;
    const float* src = img + (size_t)(y * 128 + xs) * 648;
    for (int i = t; i < total; i += 256) {
        const int x = i / (8 * nv);
        const int rem = i - x * (8 * nv);
        const int c = rem / nv;
        const int vi = rem - c * nv;
        tile[(x * 8 + c) * 85 + vi] = src[x * 648 + c * 81 + v0 + vi];
    }
    __syncthreads();
    for (int i = t; i < total; i += 256) {
        const int vi = i >> 7;
        const int x = (i >> 3) & 15;
        const int c = i & 7;
        T[((size_t)(vi * 128 + y) * 128 + xs + x) * 8 + c] = tile[(x * 8 + c) * 85 + vi];
    }
}

__device__ inline unsigned int pack_pair(float a, float b, unsigned int& lw)
{
    const unsigned int ha = __float_as_uint(a) & 0xffff0000u;
    const unsigned int hb = __float_as_uint(b) & 0xffff0000u;
    const float ra = a - __uint_as_float(ha);
    const float rb = b - __uint_as_float(hb);
    lw = (__float_as_uint(ra) >> 16) | (__float_as_uint(rb) & 0xffff0000u);
    return (ha >> 16) | hb;
}

__device__ inline bhalf8_t to_b8(unsigned int a, unsigned int b,
                                 unsigned int c, unsigned int d)
{
    union { uint4 q; bhalf8_t h; } u;
    u.q = make_uint4(a, b, c, d);
    return u.h;
}

// Staged gather: issue loads early, consume (interp+pack) late.
struct GatherRegs {
    float4 a00, b00, a01, b01, a10, b10, a11, b11;
    float w00, w01, w10, w11, gate;
};

__device__ inline void gather_issue(int v, float dlt, float ix0, float iy0,
    int xgbase, const float* __restrict__ xg, const float* __restrict__ T,
    GatherRegs& g)
{
    const int vc = (v < 81) ? v : 80;
    g.gate = (v < 81) ? xg[xgbase + v] : 0.0f;
    const int uu = vc % 9, vv = vc / 9;
    const float ix = fmaf((float)(4 - uu), dlt, ix0);
    const float iy = fmaf((float)(4 - vv), dlt, iy0);
    const float x0f = floorf(ix), y0f = floorf(iy);
    const float wx1 = ix - x0f, wy1 = iy - y0f;
    const float wx0 = 1.0f - wx1, wy0 = 1.0f - wy1;
    const int x0 = (int)x0f, y0 = (int)y0f;
    const int x1 = x0 + 1, y1 = y0 + 1;
    const float ex0 = (x0 >= 0 && x0 < 128) ? wx0 : 0.0f;
    const float ex1 = (x1 >= 0 && x1 < 128) ? wx1 : 0.0f;
    const float ey0 = (y0 >= 0 && y0 < 128) ? wy0 : 0.0f;
    const float ey1 = (y1 >= 0 && y1 < 128) ? wy1 : 0.0f;
    const int xc0 = min(max(x0, 0), 127), xc1 = min(max(x1, 0), 127);
    const int yc0 = min(max(y0, 0), 127), yc1 = min(max(y1, 0), 127);
    g.w00 = ex0 * ey0; g.w01 = ex1 * ey0;
    g.w10 = ex0 * ey1; g.w11 = ex1 * ey1;
    const float* bv = T + (size_t)vc * VIEW_FLOATS;
    const float4* p00 = (const float4*)(bv + (yc0 * 128 + xc0) * 8);
    const float4* p01 = (const float4*)(bv + (yc0 * 128 + xc1) * 8);
    const float4* p10 = (const float4*)(bv + (yc1 * 128 + xc0) * 8);
    const float4* p11 = (const float4*)(bv + (yc1 * 128 + xc1) * 8);
    g.a00 = p00[0]; g.b00 = p00[1];
    g.a01 = p01[0]; g.b01 = p01[1];
    g.a10 = p10[0]; g.b10 = p10[1];
    g.a11 = p11[0]; g.b11 = p11[1];
}

__device__ inline void gather_consume(const GatherRegs& g, uint4& hi, uint4& lo)
{
    const float s0 = fmaf(g.w11, g.a11.x, fmaf(g.w10, g.a10.x, fmaf(g.w01, g.a01.x, g.w00 * g.a00.x)));
    const float s1 = fmaf(g.w11, g.a11.y, fmaf(g.w10, g.a10.y, fmaf(g.w01, g.a01.y, g.w00 * g.a00.y)));
    const float s2 = fmaf(g.w11, g.a11.z, fmaf(g.w10, g.a10.z, fmaf(g.w01, g.a01.z, g.w00 * g.a00.z)));
    const float s3 = fmaf(g.w11, g.a11.w, fmaf(g.w10, g.a10.w, fmaf(g.w01, g.a01.w, g.w00 * g.a00.w)));
    const float s4 = fmaf(g.w11, g.b11.x, fmaf(g.w10, g.b10.x, fmaf(g.w01, g.b01.x, g.w00 * g.b00.x)));
    const float s5 = fmaf(g.w11, g.b11.y, fmaf(g.w10, g.b10.y, fmaf(g.w01, g.b01.y, g.w00 * g.b00.y)));
    const float s6 = fmaf(g.w11, g.b11.z, fmaf(g.w10, g.b10.z, fmaf(g.w01, g.b01.z, g.w00 * g.b00.z)));
    const float s7 = fmaf(g.w11, g.b11.w, fmaf(g.w10, g.b10.w, fmaf(g.w01, g.b01.w, g.w00 * g.b00.w)));
    unsigned int lw0, lw1, lw2, lw3;
    const unsigned int hw0 = pack_pair(s0 * g.gate, s1 * g.gate, lw0);
    const unsigned int hw1 = pack_pair(s2 * g.gate, s3 * g.gate, lw1);
    const unsigned int hw2 = pack_pair(s4 * g.gate, s5 * g.gate, lw2);
    const unsigned int hw3 = pack_pair(s6 * g.gate, s7 * g.gate, lw3);
    hi = make_uint4(hw0, hw1, hw2, hw3);
    lo = make_uint4(lw0, lw1, lw2, lw3);
}

// ---------------------------------------------------------------------------
// Pipelined build: 128-thread blocks (2 waves, 32 positions), grid 2048.
// Sampling: thread t -> view-in-chunk sg=t>>5 (32-consecutive-pos coalescing),
// pos sp=t&31. Double-buffered LDS A-tile, ONE barrier per chunk; chunk i+1's
// gather issued before chunk i's MFMAs, consumed after -> latency hidden.
// ---------------------------------------------------------------------------
__global__ __launch_bounds__(128, 4) void build_pipe(
    const float* __restrict__ delt, const float* __restrict__ xg,
    const float* __restrict__ T, const unsigned short* __restrict__ WtP,
    const float* __restrict__ bias, float* __restrict__ out)
{
    __shared__ __align__(16) unsigned short Ahi[2][4][32][8];  // [buf][g][pos][e]
    __shared__ __align__(16) unsigned short Alo[2][4][32][8];

    const int t = threadIdx.x;
    const int wv = t >> 6;              // 0..1 (compute wave)
    const int lane = t & 63;
    const int sg = t >> 5;              // 0..3 sampling view-in-chunk
    const int sp = t & 31;              // 0..31 sampling position
    const int pos_s = blockIdx.x * 32 + sp;      // < 65536
    const int h_s = pos_s >> 9;
    const int w_s = (pos_s >> 2) & 127;
    const float dlt = delt[pos_s];
    const float ix0 = fmaf((float)w_s, 128.0f / 127.0f, -0.5f);
    const float iy0 = fmaf((float)h_s, 128.0f / 127.0f, -0.5f);
    const int xgbase = (h_s * 128 + w_s) * 81;

    const int frow = lane & 15;
    const int fg = lane >> 4;

    f32x4_t acc[4];
#pragma unroll
    for (int j = 0; j < 4; ++j) acc[j] = (f32x4_t)0.0f;

    // prologue: sample chunk 0
    uint4 hiN, loN;
    {
        GatherRegs gr;
        gather_issue(sg, dlt, ix0, iy0, xgbase, xg, T, gr);
        gather_consume(gr, hiN, loN);
    }

    for (int ci = 0; ci < KCHUNKS; ++ci) {
        const int cur = ci & 1;
        *(uint4*)(&Ahi[cur][sg][sp][0]) = hiN;
        *(uint4*)(&Alo[cur][sg][sp][0]) = loN;
        __syncthreads();

        // issue gather for chunk ci+1 (loads in flight across the MFMAs)
        GatherRegs gr;
        const bool have = (ci + 1 < KCHUNKS);
        if (have)
            gather_issue((ci + 1) * 4 + sg, dlt, ix0, iy0, xgbase, xg, T, gr);

        // fragments for chunk ci
        const int r = wv * 16 + frow;
        const bhalf8_t fa_hi = *(const bhalf8_t*)(&Ahi[cur][fg][r][0]);
        const bhalf8_t fa_lo = *(const bhalf8_t*)(&Alo[cur][fg][r][0]);
        const unsigned short* wbase = WtP + ci * 4096 + fg * 512;
        bhalf8_t fw_hi[4], fw_lo[4];
#pragma unroll
        for (int j = 0; j < 4; ++j) {
            const int o = j * 16 + frow;
            fw_hi[j] = *(const bhalf8_t*)(wbase + o * 8);
            fw_lo[j] = *(const bhalf8_t*)(wbase + 2048 + o * 8);
        }
#pragma unroll
        for (int j = 0; j < 4; ++j) {
            acc[j] = __builtin_amdgcn_mfma_f32_16x16x32_bf16(fa_hi, fw_hi[j], acc[j], 0, 0, 0);
            acc[j] = __builtin_amdgcn_mfma_f32_16x16x32_bf16(fa_lo, fw_hi[j], acc[j], 0, 0, 0);
            acc[j] = __builtin_amdgcn_mfma_f32_16x16x32_bf16(fa_hi, fw_lo[j], acc[j], 0, 0, 0);
        }

        // consume gather ci+1 (waits on its loads only now)
        if (have) gather_consume(gr, hiN, loN);
        // next iteration's LDS write (to buf cur^1) is fenced by that
        // iteration's __syncthreads(); reads this iter were from buf cur.
    }

    // D layout: col(=o)=lane&15, row(=pos)=(lane>>4)*4+reg.
    const int posb = blockIdx.x * 32 + wv * 16 + fg * 4;
#pragma unroll
    for (int j = 0; j < 4; ++j) {
        const int o = j * 16 + frow;
        const float bb = bias[o];
        float* dst = out + (size_t)o * NPOS + posb;
        *(float4*)dst = make_float4(acc[j][0] + bb, acc[j][1] + bb,
                                    acc[j][2] + bb, acc[j][3] + bb);
    }
}

// ---------------------------------------------------------------------------
// Register-direct build (multi-pass fallback path, r12-proven).
// ---------------------------------------------------------------------------
__global__ __launch_bounds__(256, 4) void build_reg(
    const float* __restrict__ delt, const float* __restrict__ xg,
    const float* __restrict__ T, const unsigned short* __restrict__ WtP,
    const float* __restrict__ bias, float* __restrict__ out,
    int kc0, int nkc, int first)
{
    const int t = threadIdx.x;
    const int frow = t & 15;
    const int fg = (t >> 4) & 3;
    const int wv = t >> 6;
    const int pos = blockIdx.x * 64 + wv * 16 + frow;
    const int h = pos >> 9;
    const int w = (pos >> 2) & 127;

    const float dlt = delt[pos];
    const float ix0 = fmaf((float)w, 128.0f / 127.0f, -0.5f);
    const float iy0 = fmaf((float)h, 128.0f / 127.0f, -0.5f);
    const int xgbase = (h * 128 + w) * 81;

    f32x4_t acc[4];
#pragma unroll
    for (int j = 0; j < 4; ++j) acc[j] = (f32x4_t)0.0f;

    for (int ci = 0; ci < nkc; ++ci) {
        const int kc = kc0 + ci;
        const int v = kc * 4 + fg;
        GatherRegs gr;
        gather_issue(v, dlt, ix0, iy0, xgbase, xg,
                     T - (size_t)kc0 * 4 * VIEW_FLOATS, gr);  // T holds views kc0*4..
        uint4 hi, lo;
        gather_consume(gr, hi, lo);
        const bhalf8_t fa_hi = to_b8(hi.x, hi.y, hi.z, hi.w);
        const bhalf8_t fa_lo = to_b8(lo.x, lo.y, lo.z, lo.w);

        const unsigned short* wbase = WtP + kc * 4096 + fg * 512;
        bhalf8_t fw_hi[4], fw_lo[4];
#pragma unroll
        for (int j = 0; j < 4; ++j) {
            const int o = j * 16 + frow;
            fw_hi[j] = *(const bhalf8_t*)(wbase + o * 8);
            fw_lo[j] = *(const bhalf8_t*)(wbase + 2048 + o * 8);
        }
#pragma unroll
        for (int j = 0; j < 4; ++j) {
            acc[j] = __builtin_amdgcn_mfma_f32_16x16x32_bf16(fa_hi, fw_hi[j], acc[j], 0, 0, 0);
            acc[j] = __builtin_amdgcn_mfma_f32_16x16x32_bf16(fa_lo, fw_hi[j], acc[j], 0, 0, 0);
            acc[j] = __builtin_amdgcn_mfma_f32_16x16x32_bf16(fa_hi, fw_lo[j], acc[j], 0, 0, 0);
        }
    }

    const int posb = blockIdx.x * 64 + wv * 16 + fg * 4;
#pragma unroll
    for (int j = 0; j < 4; ++j) {
        const int o = j * 16 + frow;
        float* dst = out + (size_t)o * NPOS + posb;
        if (first) {
            const float bb = bias[o];
            *(float4*)dst = make_float4(acc[j][0] + bb, acc[j][1] + bb,
                                        acc[j][2] + bb, acc[j][3] + bb);
        } else {
            float4 cur = *(const float4*)dst;
            *(float4*)dst = make_float4(cur.x + acc[j][0], cur.y + acc[j][1],
                                        cur.z + acc[j][2], cur.w + acc[j][3]);
        }
    }
}

// ---------------------------------------------------------------------------
// Ultra-fallback (no workspace): gather from native [y][x][c][v] layout.
// ---------------------------------------------------------------------------
__global__ __launch_bounds__(256) void build_direct(
    const float* __restrict__ delt, const float* __restrict__ xg,
    const float* __restrict__ img, const float* __restrict__ cw,
    const float* __restrict__ bias, float* __restrict__ out)
{
    const int t = threadIdx.x;
    const int frow = t & 15;
    const int fg = (t >> 4) & 3;
    const int wv = t >> 6;
    const int pos = blockIdx.x * 64 + wv * 16 + frow;
    const int h = pos >> 9;
    const int w = (pos >> 2) & 127;

    const float dlt = delt[pos];
    const float ix0 = fmaf((float)w, 128.0f / 127.0f, -0.5f);
    const float iy0 = fmaf((float)h, 128.0f / 127.0f, -0.5f);
    const int xgbase = (h * 128 + w) * 81;

    f32x4_t acc[4];
#pragma unroll
    for (int j = 0; j < 4; ++j) acc[j] = (f32x4_t)0.0f;

    for (int kc = 0; kc < KCHUNKS; ++kc) {
        const int v = kc * 4 + fg;
        float sc[8];
#pragma unroll
        for (int c = 0; c < 8; ++c) sc[c] = 0.0f;
        float gate = 0.0f;
        if (v < 81) {
            gate = xg[xgbase + v];
            const int uu = v % 9, vv = v / 9;
            const float ix = fmaf((float)(4 - uu), dlt, ix0);
            const float iy = fmaf((float)(4 - vv), dlt, iy0);
            const float x0f = floorf(ix), y0f = floorf(iy);
            const float wx1 = ix - x0f, wy1 = iy - y0f;
            const float wx0 = 1.0f - wx1, wy0 = 1.0f - wy1;
            const int x0 = (int)x0f, y0 = (int)y0f;
            const int x1 = x0 + 1, y1 = y0 + 1;
            const float ex0 = (x0 >= 0 && x0 < 128) ? wx0 : 0.0f;
            const float ex1 = (x1 >= 0 && x1 < 128) ? wx1 : 0.0f;
            const float ey0 = (y0 >= 0 && y0 < 128) ? wy0 : 0.0f;
            const float ey1 = (y1 >= 0 && y1 < 128) ? wy1 : 0.0f;
            const int xc0 = min(max(x0, 0), 127), xc1 = min(max(x1, 0), 127);
            const int yc0 = min(max(y0, 0), 127), yc1 = min(max(y1, 0), 127);
            const float cwt[4] = {ex0 * ey0, ex1 * ey0, ex0 * ey1, ex1 * ey1};
            const int cyx[4] = {yc0 * 128 + xc0, yc0 * 128 + xc1,
                                yc1 * 128 + xc0, yc1 * 128 + xc1};
#pragma unroll
            for (int k = 0; k < 4; ++k) {
                const float* p = img + (size_t)cyx[k] * 648 + v;
#pragma unroll
                for (int c = 0; c < 8; ++c)
                    sc[c] = fmaf(cwt[k], p[c * 81], sc[c]);
            }
        }
        unsigned int hw[4], lw[4];
#pragma unroll
        for (int q = 0; q < 4; ++q)
            hw[q] = pack_pair(sc[2 * q] * gate, sc[2 * q + 1] * gate, lw[q]);
        const bhalf8_t fa_hi = to_b8(hw[0], hw[1], hw[2], hw[3]);
        const bhalf8_t fa_lo = to_b8(lw[0], lw[1], lw[2], lw[3]);

        bhalf8_t fw_hi[4], fw_lo[4];
#pragma unroll
        for (int j = 0; j < 4; ++j) {
            const int o = j * 16 + frow;
#pragma unroll
            for (int e = 0; e < 8; ++e) {
                const float val = (v < 81) ? cw[o * 648 + e * 81 + v] : 0.0f;
                const unsigned int hb = __float_as_uint(val) & 0xffff0000u;
                const float r = val - __uint_as_float(hb);
                fw_hi[j][e] = (short)(hb >> 16);
                fw_lo[j][e] = (short)(__float_as_uint(r) >> 16);
            }
        }
#pragma unroll
        for (int j = 0; j < 4; ++j) {
            acc[j] = __builtin_amdgcn_mfma_f32_16x16x32_bf16(fa_hi, fw_hi[j], acc[j], 0, 0, 0);
            acc[j] = __builtin_amdgcn_mfma_f32_16x16x32_bf16(fa_lo, fw_hi[j], acc[j], 0, 0, 0);
            acc[j] = __builtin_amdgcn_mfma_f32_16x16x32_bf16(fa_hi, fw_lo[j], acc[j], 0, 0, 0);
        }
    }

    const int posb = blockIdx.x * 64 + wv * 16 + fg * 4;
#pragma unroll
    for (int j = 0; j < 4; ++j) {
        const int o = j * 16 + frow;
        const float bb = bias[o];
        float* dst = out + (size_t)o * NPOS + posb;
        *(float4*)dst = make_float4(acc[j][0] + bb, acc[j][1] + bb,
                                    acc[j][2] + bb, acc[j][3] + bb);
    }
}

extern "C" void kernel_launch(void* const* d_in, const int* in_sizes, int n_in,
                              void* d_out, int out_size, void* d_ws, size_t ws_size,
                              hipStream_t stream)
{
    const float* deltmap = (const float*)d_in[0];
    const float* image   = (const float*)d_in[1];
    const float* xgp     = (const float*)d_in[2];
    const float* cw      = (const float*)d_in[3];
    const float* cb      = (const float*)d_in[4];
    float* outp = (float*)d_out;

    unsigned short* WtP = (unsigned short*)d_ws;
    float* T = (float*)((char*)d_ws + W_BYTES);

    const bool okT = ws_size >= (size_t)W_BYTES + T_BYTES;

    if (okT) {
        prep_w_kernel<<<64, 256, 0, stream>>>(cw, WtP);
        prep_T_all<<<1024, 256, 0, stream>>>(image, T);
        build_pipe<<<2048, 128, 0, stream>>>(deltmap, xgp, T, WtP, cb, outp);
    } else {
        long long availT = (long long)ws_size - (long long)W_BYTES;
        int G = 0;
        if (availT > 0) {
            long long g = availT / CHUNK_BYTES;
            G = (g > 21) ? 21 : (int)g;
        }
        if (G >= 1) {
            prep_w_kernel<<<64, 256, 0, stream>>>(cw, WtP);
            int first = 1;
            for (int kc0 = 0; kc0 < KCHUNKS; kc0 += G) {
                const int nkc = (KCHUNKS - kc0 < G) ? (KCHUNKS - kc0) : G;
                const int v0 = kc0 * 4;
                int nv = 81 - v0;
                if (nv > nkc * 4) nv = nkc * 4;
                prep_T_pass<<<1024, 256, 0, stream>>>(image, T, v0, nv);
                build_reg<<<1024, 256, 0, stream>>>(deltmap, xgp, T, WtP, cb, outp,
                                                    kc0, nkc, first);
                first = 0;
            }
        } else {
            build_direct<<<1024, 256, 0, stream>>>(deltmap, xgp, image, cw, cb, outp);
        }
    }
}